// Round 1
// baseline (166.961 us; speedup 1.0000x reference)
//
#include <hip/hip_runtime.h>
#include <math.h>

// Problem constants (from reference): B=64, IN=1024, OUT=512, T=512, V_TH=1, TAU=16
#define BATCH   64
#define INS     1024
#define OUTS    512
#define TSTEPS  512
#define TAUF    16.0f

// ---------------------------------------------------------------------------
// Kernel 1: transpose weight [OUT, IN] -> wT [IN, OUT] so the scan kernel's
// per-spike weight read (fixed i, lane-varying o) is coalesced.
// ---------------------------------------------------------------------------
__global__ __launch_bounds__(256) void transpose_w_kernel(
        const float* __restrict__ w, float* __restrict__ wT) {
    int j = blockIdx.x * 256 + threadIdx.x;   // j over IN*OUT
    int o = j & (OUTS - 1);
    int i = j >> 9;                            // OUTS = 512 = 2^9
    wT[j] = w[o * INS + i];                    // coalesced write, strided (L2-cached) read
}

// ---------------------------------------------------------------------------
// Kernel 2: per-batch spike preprocessing + counting sort by activation time.
// alpha(t-s) = e^{-t/tau} * (t*A + C) for t > s, with
//   A = exp(1 + s/tau)/tau,  C = -s*A,  t_on = floor(s)+1 in [1,256].
// Output record per spike: {A, C, (float)t_on, (float)i}, sorted by t_on.
// One block per b, 256 threads.
// ---------------------------------------------------------------------------
__global__ __launch_bounds__(256) void spike_prep_kernel(
        const float* __restrict__ in_spike, float4* __restrict__ spk) {
    const int b = blockIdx.x;
    __shared__ int hist[257];
    __shared__ int cursor[257];

    for (int k = threadIdx.x; k < 257; k += 256) hist[k] = 0;
    __syncthreads();

    float sv[INS / 256];
    int   tv[INS / 256];
#pragma unroll
    for (int j = 0; j < INS / 256; ++j) {
        int i = threadIdx.x + j * 256;
        float s = in_spike[b * INS + i];
        sv[j] = s;
        int t = (int)floorf(s) + 1;            // activation step
        t = t < 1 ? 1 : (t > 256 ? 256 : t);   // safety clamp (s in [0,256))
        tv[j] = t;
        atomicAdd(&hist[t], 1);
    }
    __syncthreads();

    if (threadIdx.x == 0) {                    // tiny serial exclusive scan (256 buckets)
        int acc = 0;
        for (int t = 1; t <= 256; ++t) { cursor[t] = acc; acc += hist[t]; }
    }
    __syncthreads();

#pragma unroll
    for (int j = 0; j < INS / 256; ++j) {
        int i = threadIdx.x + j * 256;
        int t = tv[j];
        int pos = atomicAdd(&cursor[t], 1);    // within-bucket order irrelevant
        float A = expf(fmaf(sv[j], 1.0f / TAUF, 1.0f)) * (1.0f / TAUF);
        float C = -sv[j] * A;
        spk[b * INS + pos] = make_float4(A, C, (float)t, (float)i);
    }
}

// ---------------------------------------------------------------------------
// Kernel 3: per-(b,o) forward scan.  Spikes (sorted by t_on, shared across the
// block's outputs) stream from LDS as broadcast float4 reads; weights gather
// coalesced from wT.  Between consecutive t_on values we test
//   V(t) >= 1   <=>   fma(t, SA, SC) >= exp(t/tau)   (LDS table)
// Block = (b, chunk of 128 outputs) -> 64*4 = 256 blocks, 128 threads.
// ---------------------------------------------------------------------------
#define BD 128

__global__ __launch_bounds__(BD) void spike_scan_kernel(
        const float4* __restrict__ spk, const float* __restrict__ wT,
        float* __restrict__ out) {
    const int b = blockIdx.x;
    const int o = blockIdx.y * BD + (int)threadIdx.x;

    __shared__ float4 sspk[INS];    // 16 KB
    __shared__ float  sE[TSTEPS];   // 2 KB: exp(t/tau)

    const float4* bspk = spk + b * INS;
    for (int k = threadIdx.x; k < INS; k += BD) sspk[k] = bspk[k];
    for (int t = threadIdx.x; t < TSTEPS; t += BD) sE[t] = expf((float)t * (1.0f / TAUF));
    __syncthreads();

    float SA = 0.f, SC = 0.f;
    int tcur = 1;
    int first = TSTEPS;

#define ADVANCE_TO(TK)                                                        \
    while (tcur < (TK)) {                                                     \
        float v = fmaf((float)tcur, SA, SC);                                  \
        if (v >= sE[tcur] && tcur < first) first = tcur;                      \
        ++tcur;                                                               \
    }

    for (int k = 0; k < INS; k += 4) {
        // 4-deep prefetch: issue all LDS + global loads up front
        float4 p0 = sspk[k + 0];
        float4 p1 = sspk[k + 1];
        float4 p2 = sspk[k + 2];
        float4 p3 = sspk[k + 3];
        float w0 = wT[((int)p0.w) * OUTS + o];
        float w1 = wT[((int)p1.w) * OUTS + o];
        float w2 = wT[((int)p2.w) * OUTS + o];
        float w3 = wT[((int)p3.w) * OUTS + o];

        int tk;
        tk = (int)p0.z; ADVANCE_TO(tk);
        SA = fmaf(w0, p0.x, SA); SC = fmaf(w0, p0.y, SC);
        tk = (int)p1.z; ADVANCE_TO(tk);
        SA = fmaf(w1, p1.x, SA); SC = fmaf(w1, p1.y, SC);
        tk = (int)p2.z; ADVANCE_TO(tk);
        SA = fmaf(w2, p2.x, SA); SC = fmaf(w2, p2.y, SC);
        tk = (int)p3.z; ADVANCE_TO(tk);
        SA = fmaf(w3, p3.x, SA); SC = fmaf(w3, p3.y, SC);
    }
    // tail: all spikes active; SA, SC final
    ADVANCE_TO(TSTEPS);
#undef ADVANCE_TO

    out[b * OUTS + o] = (float)first;
}

// ---------------------------------------------------------------------------
extern "C" void kernel_launch(void* const* d_in, const int* in_sizes, int n_in,
                              void* d_out, int out_size, void* d_ws, size_t ws_size,
                              hipStream_t stream) {
    const float* in_spike = (const float*)d_in[0];   // [B, IN] fp32
    const float* weight   = (const float*)d_in[1];   // [OUT, IN] fp32
    float* out = (float*)d_out;                      // [B, OUT] fp32

    // workspace layout: wT (IN*OUT floats = 2 MB) | spk (B*IN float4 = 1 MB)
    float*  wT  = (float*)d_ws;
    float4* spk = (float4*)((char*)d_ws + (size_t)INS * OUTS * sizeof(float));

    transpose_w_kernel<<<(INS * OUTS) / 256, 256, 0, stream>>>(weight, wT);
    spike_prep_kernel<<<BATCH, 256, 0, stream>>>(in_spike, spk);
    spike_scan_kernel<<<dim3(BATCH, OUTS / BD), BD, 0, stream>>>(spk, wT, out);
}

// Round 2
// 127.166 us; speedup vs baseline: 1.3129x; 1.3129x over previous
//
#include <hip/hip_runtime.h>
#include <math.h>

// Problem constants: B=64, IN=1024, OUT=512, T=512, V_TH=1, TAU=16
#define BATCH   64
#define INS     1024
#define OUTS    512
#define TSTEPS  512
#define TAUF    16.0f

// ---------------------------------------------------------------------------
// Kernel 1: tiled transpose weight [OUT, IN] -> wT [IN, OUT].
// Both global read and write coalesced; LDS tile padded +1 (no bank conflicts).
// ---------------------------------------------------------------------------
#define TT 64
__global__ __launch_bounds__(256) void transpose_w_kernel(
        const float* __restrict__ w, float* __restrict__ wT) {
    __shared__ float tile[TT][TT + 1];
    const int i0 = blockIdx.x * TT;      // IN tile base
    const int o0 = blockIdx.y * TT;      // OUT tile base
    const int c  = threadIdx.x & 63;
    const int r  = threadIdx.x >> 6;     // 0..3
#pragma unroll
    for (int rr = r; rr < TT; rr += 4)
        tile[rr][c] = w[(o0 + rr) * INS + i0 + c];
    __syncthreads();
#pragma unroll
    for (int rr = r; rr < TT; rr += 4)
        wT[(i0 + rr) * OUTS + o0 + c] = tile[c][rr];
}

// ---------------------------------------------------------------------------
// Kernel 2: per-batch spike preprocessing + counting sort by activation time.
// alpha(t-s) = e^{-t/tau} * (t*A + C) for t > s, with
//   A = exp(1 + s/tau)/tau,  C = -s*A,  t_on = floor(s)+1 in [1,256].
// Record per spike: {A, C, (float)t_on, (float)i}, sorted by t_on.
// One block per b, 256 threads; parallel Hillis-Steele bucket scan.
// ---------------------------------------------------------------------------
__global__ __launch_bounds__(256) void spike_prep_kernel(
        const float* __restrict__ in_spike, float4* __restrict__ spk) {
    const int b = blockIdx.x;
    __shared__ int hist[257];
    __shared__ int cursor[257];
    __shared__ int scanbuf[256];

    for (int k = threadIdx.x; k < 257; k += 256) hist[k] = 0;
    __syncthreads();

    float sv[INS / 256];
    int   tv[INS / 256];
#pragma unroll
    for (int j = 0; j < INS / 256; ++j) {
        int i = threadIdx.x + j * 256;
        float s = in_spike[b * INS + i];
        sv[j] = s;
        int t = (int)floorf(s) + 1;
        t = t < 1 ? 1 : (t > 256 ? 256 : t);
        tv[j] = t;
        atomicAdd(&hist[t], 1);
    }
    __syncthreads();

    // parallel exclusive scan of hist[1..256] -> cursor[1..256]
    const int tid = threadIdx.x;
    int v = hist[tid + 1];
    scanbuf[tid] = v;
    __syncthreads();
#pragma unroll
    for (int off = 1; off < 256; off <<= 1) {
        int add = (tid >= off) ? scanbuf[tid - off] : 0;
        __syncthreads();
        scanbuf[tid] += add;
        __syncthreads();
    }
    cursor[tid + 1] = scanbuf[tid] - v;   // exclusive prefix
    __syncthreads();

#pragma unroll
    for (int j = 0; j < INS / 256; ++j) {
        int i = threadIdx.x + j * 256;
        int t = tv[j];
        int pos = atomicAdd(&cursor[t], 1);
        float A = expf(fmaf(sv[j], 1.0f / TAUF, 1.0f)) * (1.0f / TAUF);
        float C = -sv[j] * A;
        spk[b * INS + pos] = make_float4(A, C, (float)t, (float)i);
    }
}

// ---------------------------------------------------------------------------
// Kernel 3: chunked forward scan.  Block = (b, 64 outputs) with 512 threads:
// threadIdx.x = output lane (64, coalesced wT gather), threadIdx.y = chunk g
// of 8.  Each thread: pass-1 partial sums over its 128 sorted spikes; LDS
// exclusive scan over g; pass-2 re-walk with threshold checks over the time
// sub-range [t_on(first spike of chunk g), t_on(first spike of chunk g+1)).
// These ranges partition the time axis, so atomicMin of per-chunk first
// crossings is exact.   V(t) >= 1  <=>  fma(t, SA, SC) >= exp(t/tau).
// ---------------------------------------------------------------------------
#define OL 64            // outputs per block
#define G  8             // chunks per output
#define CH (INS / G)     // 128 spikes per chunk

__global__ __launch_bounds__(OL * G) void spike_scan_kernel(
        const float4* __restrict__ spk, const float* __restrict__ wT,
        float* __restrict__ out) {
    const int b = blockIdx.x;
    const int x = threadIdx.x;           // 0..63 output lane
    const int g = threadIdx.y;           // 0..7 chunk
    const int o = blockIdx.y * OL + x;
    const int tid = g * OL + x;

    __shared__ float4 sspk[INS];         // 16 KB
    __shared__ float  sE[TSTEPS];        // 2 KB: exp(t/tau)
    __shared__ float  psA[G][OL];        // 2 KB
    __shared__ float  psC[G][OL];        // 2 KB
    __shared__ int    sFirst[OL];        // 256 B

    const float4* bspk = spk + b * INS;
    for (int k = tid; k < INS; k += OL * G) sspk[k] = bspk[k];
    for (int t = tid; t < TSTEPS; t += OL * G) sE[t] = expf((float)t * (1.0f / TAUF));
    if (g == 0) sFirst[x] = TSTEPS;
    __syncthreads();

    const int k0 = g * CH;

    // ---- pass 1: chunk partial sums (no checks) ----
    float pA = 0.f, pC = 0.f;
    for (int k = k0; k < k0 + CH; k += 4) {
        float4 p0 = sspk[k + 0];
        float4 p1 = sspk[k + 1];
        float4 p2 = sspk[k + 2];
        float4 p3 = sspk[k + 3];
        float w0 = wT[((int)p0.w) * OUTS + o];
        float w1 = wT[((int)p1.w) * OUTS + o];
        float w2 = wT[((int)p2.w) * OUTS + o];
        float w3 = wT[((int)p3.w) * OUTS + o];
        pA = fmaf(w0, p0.x, pA); pC = fmaf(w0, p0.y, pC);
        pA = fmaf(w1, p1.x, pA); pC = fmaf(w1, p1.y, pC);
        pA = fmaf(w2, p2.x, pA); pC = fmaf(w2, p2.y, pC);
        pA = fmaf(w3, p3.x, pA); pC = fmaf(w3, p3.y, pC);
    }
    psA[g][x] = pA; psC[g][x] = pC;
    __syncthreads();

    // ---- exclusive scan over the 8 chunks (tiny) ----
    float SA = 0.f, SC = 0.f;
    for (int j = 0; j < g; ++j) { SA += psA[j][x]; SC += psC[j][x]; }

    // time sub-range owned by this chunk
    int tcur = (int)sspk[k0].z;
    const int tend = (g == G - 1) ? TSTEPS : (int)sspk[k0 + CH].z;

    int first = TSTEPS;

#define ADVANCE_TO(TK)                                                        \
    while (tcur < (TK)) {                                                     \
        float v = fmaf((float)tcur, SA, SC);                                  \
        if (v >= sE[tcur]) { first = tcur; goto scan_done; }                  \
        ++tcur;                                                               \
    }

    // ---- pass 2: re-walk chunk with threshold checks ----
    for (int k = k0; k < k0 + CH; k += 4) {
        float4 p0 = sspk[k + 0];
        float4 p1 = sspk[k + 1];
        float4 p2 = sspk[k + 2];
        float4 p3 = sspk[k + 3];
        float w0 = wT[((int)p0.w) * OUTS + o];
        float w1 = wT[((int)p1.w) * OUTS + o];
        float w2 = wT[((int)p2.w) * OUTS + o];
        float w3 = wT[((int)p3.w) * OUTS + o];
        int tk;
        tk = (int)p0.z; ADVANCE_TO(tk);
        SA = fmaf(w0, p0.x, SA); SC = fmaf(w0, p0.y, SC);
        tk = (int)p1.z; ADVANCE_TO(tk);
        SA = fmaf(w1, p1.x, SA); SC = fmaf(w1, p1.y, SC);
        tk = (int)p2.z; ADVANCE_TO(tk);
        SA = fmaf(w2, p2.x, SA); SC = fmaf(w2, p2.y, SC);
        tk = (int)p3.z; ADVANCE_TO(tk);
        SA = fmaf(w3, p3.x, SA); SC = fmaf(w3, p3.y, SC);
    }
    // tail of this chunk's time range
    ADVANCE_TO(tend);
#undef ADVANCE_TO

scan_done:
    if (first < TSTEPS) atomicMin(&sFirst[x], first);
    __syncthreads();
    if (g == 0) out[b * OUTS + o] = (float)sFirst[x];
}

// ---------------------------------------------------------------------------
extern "C" void kernel_launch(void* const* d_in, const int* in_sizes, int n_in,
                              void* d_out, int out_size, void* d_ws, size_t ws_size,
                              hipStream_t stream) {
    const float* in_spike = (const float*)d_in[0];   // [B, IN] fp32
    const float* weight   = (const float*)d_in[1];   // [OUT, IN] fp32
    float* out = (float*)d_out;                      // [B, OUT] fp32

    float*  wT  = (float*)d_ws;                                        // 2 MB
    float4* spk = (float4*)((char*)d_ws + (size_t)INS * OUTS * sizeof(float)); // 1 MB

    transpose_w_kernel<<<dim3(INS / TT, OUTS / TT), 256, 0, stream>>>(weight, wT);
    spike_prep_kernel<<<BATCH, 256, 0, stream>>>(in_spike, spk);
    spike_scan_kernel<<<dim3(BATCH, OUTS / OL), dim3(OL, G), 0, stream>>>(spk, wT, out);
}

// Round 3
// 118.460 us; speedup vs baseline: 1.4094x; 1.0735x over previous
//
#include <hip/hip_runtime.h>
#include <math.h>

// Problem constants: B=64, IN=1024, OUT=512, T=512, V_TH=1, TAU=16
#define BATCH   64
#define INS     1024
#define OUTS    512
#define TSTEPS  512
#define TAUF    16.0f

// ---------------------------------------------------------------------------
// Fused pre-kernel: blocks [0,128) do the tiled weight transpose
// w[OUT,IN] -> wT[IN,OUT]; blocks [128,192) do per-batch spike prep +
// counting sort by activation time.
//   alpha(t-s) = e^{-t/tau} * (t*A + C) for t > s, with
//   A = exp(1 + s/tau)/tau,  C = -s*A,  t_on = floor(s)+1 in [1,256].
//   Record per spike: {A, C, (float)t_on, (float)i}, sorted by t_on.
// ---------------------------------------------------------------------------
#define TT 64
#define NTRANS ((INS / TT) * (OUTS / TT))   // 16*8 = 128 transpose blocks

__global__ __launch_bounds__(256) void pre_kernel(
        const float* __restrict__ w, float* __restrict__ wT,
        const float* __restrict__ in_spike, float4* __restrict__ spk) {
    __shared__ float tile[TT][TT + 1];           // 16.6 KB (transpose path)
    __shared__ int hist[257];
    __shared__ int cursor[257];
    __shared__ int scanbuf[256];

    if (blockIdx.x < NTRANS) {
        // ---- transpose tile ----
        const int i0 = (blockIdx.x & (INS / TT - 1)) * TT;   // IN tile base
        const int o0 = (blockIdx.x / (INS / TT)) * TT;       // OUT tile base
        const int c  = threadIdx.x & 63;
        const int r  = threadIdx.x >> 6;                     // 0..3
#pragma unroll
        for (int rr = r; rr < TT; rr += 4)
            tile[rr][c] = w[(o0 + rr) * INS + i0 + c];
        __syncthreads();
#pragma unroll
        for (int rr = r; rr < TT; rr += 4)
            wT[(i0 + rr) * OUTS + o0 + c] = tile[c][rr];
        return;
    }

    // ---- spike prep for batch b ----
    const int b = blockIdx.x - NTRANS;
    for (int k = threadIdx.x; k < 257; k += 256) hist[k] = 0;
    __syncthreads();

    float sv[INS / 256];
    int   tv[INS / 256];
#pragma unroll
    for (int j = 0; j < INS / 256; ++j) {
        int i = threadIdx.x + j * 256;
        float s = in_spike[b * INS + i];
        sv[j] = s;
        int t = (int)floorf(s) + 1;
        t = t < 1 ? 1 : (t > 256 ? 256 : t);
        tv[j] = t;
        atomicAdd(&hist[t], 1);
    }
    __syncthreads();

    // parallel exclusive scan of hist[1..256] -> cursor[1..256]
    const int tid = threadIdx.x;
    int v = hist[tid + 1];
    scanbuf[tid] = v;
    __syncthreads();
#pragma unroll
    for (int off = 1; off < 256; off <<= 1) {
        int add = (tid >= off) ? scanbuf[tid - off] : 0;
        __syncthreads();
        scanbuf[tid] += add;
        __syncthreads();
    }
    cursor[tid + 1] = scanbuf[tid] - v;   // exclusive prefix
    __syncthreads();

#pragma unroll
    for (int j = 0; j < INS / 256; ++j) {
        int i = threadIdx.x + j * 256;
        int t = tv[j];
        int pos = atomicAdd(&cursor[t], 1);
        float A = expf(fmaf(sv[j], 1.0f / TAUF, 1.0f)) * (1.0f / TAUF);
        float C = -sv[j] * A;
        spk[b * INS + pos] = make_float4(A, C, (float)t, (float)i);
    }
}

// ---------------------------------------------------------------------------
// Scan kernel.  Block = (b, 32 outputs) with 512 threads:
// threadIdx.x = output lane (32, coalesced wT gather), threadIdx.y = chunk g
// of 16 (64 sorted spikes each).  Pass 1: chunk-partial (SwA, SwC).  LDS
// exclusive scan over g.  Pass 2: re-walk own chunk interleaving threshold
// checks over the owned time range [t_on(chunk start), t_on(next chunk
// start)) — ranges partition the time axis, so atomicMin over per-chunk
// first crossings is exact.   V(t) >= 1  <=>  fma(t, SA, SC) >= exp(t/tau).
// Grid = 64 * 16 = 1024 blocks -> 4 blocks/CU, 32 waves/CU.
// ---------------------------------------------------------------------------
#define OL 32            // outputs per block
#define G  16            // chunks per output
#define CH (INS / G)     // 64 spikes per chunk

__global__ __launch_bounds__(OL * G) void spike_scan_kernel(
        const float4* __restrict__ spk, const float* __restrict__ wT,
        float* __restrict__ out) {
    const int b = blockIdx.x;
    const int x = threadIdx.x;           // 0..31 output lane
    const int g = threadIdx.y;           // 0..15 chunk
    const int o = blockIdx.y * OL + x;
    const int tid = g * OL + x;

    __shared__ float4 sspk[INS];         // 16 KB
    __shared__ float  sE[TSTEPS];        // 2 KB: exp(t/tau)
    __shared__ float  psA[G][OL];        // 2 KB
    __shared__ float  psC[G][OL];        // 2 KB
    __shared__ int    sFirst[OL];        // 128 B

    const float4* bspk = spk + b * INS;
    for (int k = tid; k < INS; k += OL * G) sspk[k] = bspk[k];
    for (int t = tid; t < TSTEPS; t += OL * G) sE[t] = expf((float)t * (1.0f / TAUF));
    if (tid < OL) sFirst[x] = TSTEPS;
    __syncthreads();

    const int k0 = g * CH;

    // ---- pass 1: chunk partial sums (no checks) ----
    float pA = 0.f, pC = 0.f;
    for (int k = k0; k < k0 + CH; k += 4) {
        float4 p0 = sspk[k + 0];
        float4 p1 = sspk[k + 1];
        float4 p2 = sspk[k + 2];
        float4 p3 = sspk[k + 3];
        float w0 = wT[((int)p0.w) * OUTS + o];
        float w1 = wT[((int)p1.w) * OUTS + o];
        float w2 = wT[((int)p2.w) * OUTS + o];
        float w3 = wT[((int)p3.w) * OUTS + o];
        pA = fmaf(w0, p0.x, pA); pC = fmaf(w0, p0.y, pC);
        pA = fmaf(w1, p1.x, pA); pC = fmaf(w1, p1.y, pC);
        pA = fmaf(w2, p2.x, pA); pC = fmaf(w2, p2.y, pC);
        pA = fmaf(w3, p3.x, pA); pC = fmaf(w3, p3.y, pC);
    }
    psA[g][x] = pA; psC[g][x] = pC;
    __syncthreads();

    // ---- exclusive scan over the G chunks (tiny) ----
    float SA = 0.f, SC = 0.f;
    for (int j = 0; j < g; ++j) { SA += psA[j][x]; SC += psC[j][x]; }

    // time sub-range owned by this chunk
    int tcur = (int)sspk[k0].z;
    const int tend = (g == G - 1) ? TSTEPS : (int)sspk[k0 + CH].z;

    int first = TSTEPS;

#define ADVANCE_TO(TK)                                                        \
    while (tcur < (TK)) {                                                     \
        float v = fmaf((float)tcur, SA, SC);                                  \
        if (v >= sE[tcur]) { first = tcur; goto scan_done; }                  \
        ++tcur;                                                               \
    }

    // ---- pass 2: re-walk chunk with threshold checks ----
    for (int k = k0; k < k0 + CH; k += 4) {
        float4 p0 = sspk[k + 0];
        float4 p1 = sspk[k + 1];
        float4 p2 = sspk[k + 2];
        float4 p3 = sspk[k + 3];
        float w0 = wT[((int)p0.w) * OUTS + o];
        float w1 = wT[((int)p1.w) * OUTS + o];
        float w2 = wT[((int)p2.w) * OUTS + o];
        float w3 = wT[((int)p3.w) * OUTS + o];
        int tk;
        tk = (int)p0.z; ADVANCE_TO(tk);
        SA = fmaf(w0, p0.x, SA); SC = fmaf(w0, p0.y, SC);
        tk = (int)p1.z; ADVANCE_TO(tk);
        SA = fmaf(w1, p1.x, SA); SC = fmaf(w1, p1.y, SC);
        tk = (int)p2.z; ADVANCE_TO(tk);
        SA = fmaf(w2, p2.x, SA); SC = fmaf(w2, p2.y, SC);
        tk = (int)p3.z; ADVANCE_TO(tk);
        SA = fmaf(w3, p3.x, SA); SC = fmaf(w3, p3.y, SC);
    }
    // tail of this chunk's time range
    ADVANCE_TO(tend);
#undef ADVANCE_TO

scan_done:
    if (first < TSTEPS) atomicMin(&sFirst[x], first);
    __syncthreads();
    if (tid < OL) out[b * OUTS + o] = (float)sFirst[x];
}

// ---------------------------------------------------------------------------
extern "C" void kernel_launch(void* const* d_in, const int* in_sizes, int n_in,
                              void* d_out, int out_size, void* d_ws, size_t ws_size,
                              hipStream_t stream) {
    const float* in_spike = (const float*)d_in[0];   // [B, IN] fp32
    const float* weight   = (const float*)d_in[1];   // [OUT, IN] fp32
    float* out = (float*)d_out;                      // [B, OUT] fp32

    float*  wT  = (float*)d_ws;                                        // 2 MB
    float4* spk = (float4*)((char*)d_ws + (size_t)INS * OUTS * sizeof(float)); // 1 MB

    pre_kernel<<<NTRANS + BATCH, 256, 0, stream>>>(weight, wT, in_spike, spk);
    spike_scan_kernel<<<dim3(BATCH, OUTS / OL), dim3(OL, G), 0, stream>>>(spk, wT, out);
}